// Round 8
// baseline (618.605 us; speedup 1.0000x reference)
//
#include <hip/hip_runtime.h>
#include <math.h>

// Problem constants
#define NXg 128
#define NYg 128
#define Pg  (NXg*NYg)      // 16384 pixels
#define Bq  64             // batch
#define Wd  64             // WIDTH (channels)
#define NKX 24             // kept kx rows: 0..11 and 116..127
#define NMODE (NKX*12)     // 288
#define PI2_128 0.04908738521234052f   // 2*pi/128

typedef _Float16 f16x8 __attribute__((ext_vector_type(8)));
typedef _Float16 f16x4 __attribute__((ext_vector_type(4)));
typedef float    f32x4 __attribute__((ext_vector_type(4)));

// ---------------- workspace layout ----------------
#define OFF_TC  0
#define OFF_TS  (OFF_TC + 128)
#define F32_END (OFF_TS + 128)
#define H_T1E  0                          // T1e  [t=32][y=128]
#define H_T1ET (H_T1E + 32*128)           // T1eT [y=128][t=32]
#define H_A2   (H_T1ET + 128*32)          // A2   [48][256]
#define H_PWH  (H_A2 + 48*256)            // PWh  [4][64][64]
#define H_T2ET (H_PWH + 4*64*64)          // T2eT [x=128][k=64]
#define H_XFHR (H_T2ET + 128*64)          // xfh  [mode=288][bc=4096] fp16
#define H_XFHI (H_XFHR + 288*4096)
#define H_OFHR (H_XFHI + 288*4096)        // ofh  [mode][bc] fp16
#define H_OFHI (H_OFHR + 288*4096)
#define H_WHR  (H_OFHI + 288*4096)        // Wh   [4][288][o=64][i=64] fp16
#define H_WHI  (H_WHR + (size_t)4*288*4096)
#define H_YG   (H_WHI + (size_t)4*288*4096)       // Yg [b][row][o][t=24]  (contiguous 3KB per (b,row))
#define H_X    (H_YG + (size_t)Bq*Wd*128*24)      // x  [b][x][y][c]
#define H_U    (H_X + (size_t)Bq*128*128*64)      // union: val/cnt | Gh

// ---------------- fast gelu: 0.5*v*(1+erf(v/sqrt2)), A&S 7.1.26 erf ----------------
__device__ __forceinline__ float fast_gelu(float v) {
    float a = fabsf(v) * 0.70710678118654752f;
    float t = 1.f / (1.f + 0.3275911f * a);
    float p = t * (0.254829592f + t * (-0.284496736f + t * (1.421413741f +
              t * (-1.453152027f + t * 1.061405429f))));
    float er = 1.f - p * __expf(-a * a);
    er = copysignf(er, v);
    return 0.5f * v * (1.f + er);
}

// ---------------- prep: tables + scatter + coalesced Wh transpose ----------------
// grid 1104 blocks x 256: blk<64 tables; 64..79 scatter; 80..1103 Wh transpose
__global__ void k_prep(_Float16* T1e_g, _Float16* T1eT_g, _Float16* A2_g,
                       const float* pww, _Float16* PWh, _Float16* T2eT_g,
                       float* Tc, float* Ts,
                       const float* xyt, const float* obs_c, const float* obs_v,
                       const int* nb, const int* siy, const int* six,
                       float* val, float* cnt,
                       const float* w1r, const float* w1i,
                       const float* w2r, const float* w2i,
                       _Float16* Whr, _Float16* Whi) {
    __shared__ _Float16 L[64][146];   // transpose tile; pad 146 -> conflict-free col reads
    int blk = blockIdx.x;
    if (blk < 64) {
        int t = blk * 256 + threadIdx.x;   // 0..16383
        if (t < 32*128) {
            int r = t >> 7, y = t & 127;
            float v = 0.f;
            if (r < 12)      v =  cosf((float)((r * y) & 127) * PI2_128);
            else if (r < 24) v = -sinf((float)(((r-12) * y) & 127) * PI2_128);
            T1e_g[t] = (_Float16)v;
            int y2 = t >> 5, r2 = t & 31;
            float v2 = 0.f;
            if (r2 < 12)      v2 =  cosf((float)((r2 * y2) & 127) * PI2_128);
            else if (r2 < 24) v2 = -sinf((float)(((r2-12) * y2) & 127) * PI2_128);
            T1eT_g[t] = (_Float16)v2;
        }
        if (t < 48*256) {
            int m = t >> 8, k = t & 255;
            int x = k & 127;
            int hi = (k >= 128);
            float v;
            if (m < 24) {
                int kx = (m < 12) ? m : (104 + m);
                float th = (float)((kx * x) & 127) * PI2_128;
                v = hi ? sinf(th) : cosf(th);
            } else {
                int mm = m - 24;
                int kx = (mm < 12) ? mm : (104 + mm);
                float th = (float)((kx * x) & 127) * PI2_128;
                v = hi ? cosf(th) : -sinf(th);
            }
            A2_g[t] = (_Float16)v;
        }
        if (t < 4*64*64) PWh[t] = (_Float16)pww[t];
        if (t < 128*64) {
            int x = t >> 6, k = t & 63;
            float v = 0.f;
            if (k < 24) {
                int kx = (k < 12) ? k : (104 + k);
                v = cosf((float)((kx * x) & 127) * PI2_128);
            } else if (k < 48) {
                int kk = k - 24;
                int kx = (kk < 12) ? kk : (104 + kk);
                v = sinf((float)((kx * x) & 127) * PI2_128);
            }
            T2eT_g[t] = (_Float16)v;
        }
        if (t < 128) {
            float th = (float)t * PI2_128;
            Tc[t] = cosf(th);
            Ts[t] = sinf(th);
        }
    } else if (blk < 80) {
        int t = (blk - 64) * 256 + threadIdx.x;   // 0..4095 = B*K
        int b = t >> 6;
        int id = nb[t];
        int sid = id / 50;                        // NT = 50
        float tq = xyt[b*3 + 2];
        float w = expf(-0.1f * fabsf(obs_c[id*3 + 2] - tq));
        int lin = siy[sid] * NYg + six[sid];
        atomicAdd(&val[b*Pg + lin], obs_v[id] * w);
        atomicAdd(&cnt[b*Pg + lin], w);
    } else {
        // coalesced Wh transpose: src [layer][i=64][o=64][m=144] f32 (contiguous m)
        //                         dst Wh[(layer*288 + half*144 + m)*4096 + o*64 + i]
        int u = blk - 80;                 // 0..1023
        int layer = u >> 8;
        int rem = u & 255;
        int o = rem & 63, ri = (rem >> 6) & 1, half = rem >> 7;
        const float* src = half ? (ri ? w2i : w2r) : (ri ? w1i : w1r);
        _Float16* dst = ri ? Whi : Whr;
        size_t sbase = (size_t)layer * 589824 + (size_t)o * 144;
        for (int idx = threadIdx.x; idx < 9216; idx += 256) {
            int i = idx / 144, m = idx - i*144;
            L[i][m] = (_Float16)src[sbase + (size_t)i*9216 + m];
        }
        __syncthreads();
        size_t obase = ((size_t)(layer*288 + half*144) << 12) + o*64;
        for (int idx = threadIdx.x; idx < 9216; idx += 256) {
            int m = idx >> 6, i = idx & 63;
            dst[obase + ((size_t)m << 12) + i] = L[i][m];
        }
    }
}

// ---------------- stage-A y-DFT epilogue ----------------
__device__ __forceinline__ void stageA_bf(const _Float16* __restrict__ T1e_g, int lane, f16x8* bf) {
    int l15 = lane & 15, quad = lane >> 4;
    #pragma unroll
    for (int u = 0; u < 8; u++) {
        int nt2 = u >> 2, q = u & 3;
        bf[u] = *(const f16x8*)&T1e_g[(nt2*16 + l15)*128 + q*32 + quad*8];
    }
}

// load A-fragments (Xn columns) for one row tile
__device__ __forceinline__ void stageA_af(const _Float16 (*Xn)[76], int tid, f16x8* af) {
    int wave = tid >> 6, lane = tid & 63;
    int l15 = lane & 15, quad = lane >> 4;
    #pragma unroll
    for (int q = 0; q < 4; q++)
        #pragma unroll
        for (int j = 0; j < 8; j++)
            af[q][j] = Xn[q*32 + quad*8 + j][wave*16 + l15];
}

// MFMA + write result to LDS Yl[o=64][t=24] (o-major, t contiguous)
__device__ __forceinline__ void stageA_lds(const f16x8* af, const f16x8* bf,
                                           _Float16* Yl, int tid) {
    int wave = tid >> 6, lane = tid & 63;
    int l15 = lane & 15, quad = lane >> 4;
    #pragma unroll
    for (int nt2 = 0; nt2 < 2; nt2++) {
        f32x4 acc = {0.f,0.f,0.f,0.f};
        #pragma unroll
        for (int q = 0; q < 4; q++)
            acc = __builtin_amdgcn_mfma_f32_16x16x32_f16(af[q], bf[nt2*4 + q], acc, 0, 0, 0);
        int t = nt2*16 + l15;
        if (t < 24) {
            #pragma unroll
            for (int r = 0; r < 4; r++)
                Yl[(wave*16 + quad*4 + r)*24 + t] = (_Float16)acc[r];
        }
    }
}

// ---------------- fc0-lite: compute fc0 + stage-A only ----------------
__global__ __launch_bounds__(256) void k_fc0y(const float* __restrict__ val, const float* __restrict__ cnt,
                      const float* __restrict__ xg, const float* __restrict__ yg,
                      const float* __restrict__ w, const float* __restrict__ bb,
                      const _Float16* __restrict__ T1e_g,
                      _Float16* __restrict__ Yg) {
    __shared__ _Float16 Xn[128][76];
    __shared__ float wl[4][64];
    int row = blockIdx.x, b = blockIdx.y;
    int tid = threadIdx.x;
    if (tid < 64) {
        wl[0][tid] = w[tid]; wl[1][tid] = w[64+tid]; wl[2][tid] = w[128+tid]; wl[3][tid] = bb[tid];
    }
    __syncthreads();
    {
        int y = tid & 127, half = tid >> 7;
        int p = row*128 + y;
        float c = cnt[(size_t)b*Pg + p];
        float g = (c > 0.f) ? val[(size_t)b*Pg + p] / fmaxf(c, 1e-6f) : 0.f;
        float a1 = xg[p], a2 = yg[p];
        #pragma unroll
        for (int blk = 0; blk < 4; blk++) {
            f16x8 pk;
            #pragma unroll
            for (int j = 0; j < 8; j++) {
                int o = half*32 + blk*8 + j;
                pk[j] = (_Float16)(g*wl[0][o] + a1*wl[1][o] + a2*wl[2][o] + wl[3][o]);
            }
            *(f16x8*)&Xn[y][half*32 + blk*8] = pk;
        }
    }
    __syncthreads();
    f16x8 bf[8];
    stageA_bf(T1e_g, tid & 63, bf);
    f16x8 af[4];
    stageA_af(Xn, tid, af);
    __syncthreads();                       // all Xn reads done before reuse
    _Float16* Yl = &Xn[0][0];              // reuse Xn as [64][24] staging
    stageA_lds(af, bf, Yl, tid);
    __syncthreads();
    if (tid < 192)
        ((float4*)(Yg + (size_t)(b*128 + row) * 1536))[tid] = ((const float4*)Yl)[tid];
}

// ---------------- sB: stage-B x-DFT via MFMA, 4 bc per block ----------------
// grid 1024 x 256. Wave w computes bc = 4*blk + w over 3 m-tiles.
// Yg layout [b][x][o][t=24]: block's 4 c are consecutive within one b ->
// 96 contiguous elems (192 B) per x.
__global__ __launch_bounds__(256) void k_sB(const _Float16* __restrict__ Yg,
                    const _Float16* __restrict__ A2_g,
                    _Float16* __restrict__ xfhr, _Float16* __restrict__ xfhi) {
    __shared__ _Float16 Ys[4][28][136];
    int bc4 = blockIdx.x << 2;
    int tid = threadIdx.x;
    int wave = tid >> 6, lane = tid & 63;
    int l15 = lane & 15, quad = lane >> 4;
    int b = bc4 >> 6, c0 = bc4 & 63;
    const _Float16* base = Yg + ((size_t)b*128*64 + c0)*24;   // + x*1536
    for (int i = tid; i < 1536; i += 256) {
        int x = i / 12, w = i - x*12;
        f16x8 v = *(const f16x8*)&base[(size_t)x*1536 + w*8];
        int e = w*8;
        #pragma unroll
        for (int j = 0; j < 8; j++) {
            int tt = e + j;                // 0..95
            int s = tt / 24, t = tt - s*24;
            Ys[s][t][x] = v[j];
        }
    }
    __syncthreads();
    int bc = bc4 + wave;
    #pragma unroll
    for (int mt = 0; mt < 3; mt++) {
        f32x4 acc = {0.f,0.f,0.f,0.f};
        #pragma unroll
        for (int q = 0; q < 8; q++) {
            f16x8 a = *(const f16x8*)&A2_g[(size_t)(mt*16 + l15)*256 + q*32 + quad*8];
            const _Float16* brow = (q < 4) ? &Ys[wave][l15][q*32 + quad*8]
                                           : &Ys[wave][12 + l15][(q-4)*32 + quad*8];
            f16x8 bfr = *(const f16x8*)brow;
            acc = __builtin_amdgcn_mfma_f32_16x16x32_f16(a, bfr, acc, 0, 0, 0);
        }
        if (l15 < 12) {
            #pragma unroll
            for (int r = 0; r < 4; r++) {
                int m = mt*16 + quad*4 + r;
                if (m < 24) xfhr[(size_t)(m*12 + l15)*4096 + bc] = (_Float16)acc[r];
                else        xfhi[(size_t)((m-24)*12 + l15)*4096 + bc] = (_Float16)acc[r];
            }
        }
    }
}

// ---------------- s3m: mode mixing via MFMA, 4-way batch split ----------------
__global__ __launch_bounds__(256) void k_s3m(const _Float16* __restrict__ xfhr, const _Float16* __restrict__ xfhi,
                    const _Float16* __restrict__ Whr, const _Float16* __restrict__ Whi,
                    _Float16* __restrict__ ofhr, _Float16* __restrict__ ofhi, int layer) {
    __shared__ _Float16 Xr[16][72], Xi[16][72];
    int mode = blockIdx.x;
    int bo = blockIdx.y << 4;          // batch offset: 0,16,32,48
    int tid = threadIdx.x;
    int wave = tid >> 6, lane = tid & 63;
    int l15 = lane & 15, quad = lane >> 4;
    const _Float16* pr = xfhr + (size_t)mode * 4096 + bo*64;
    const _Float16* pi = xfhi + (size_t)mode * 4096 + bo*64;
    if (tid < 128) {
        int b = tid >> 3, seg = tid & 7;
        *(f16x8*)&Xr[b][seg*8] = *(const f16x8*)&pr[tid*8];
        *(f16x8*)&Xi[b][seg*8] = *(const f16x8*)&pi[tid*8];
    }
    __syncthreads();
    size_t wb = ((size_t)(layer*288 + mode)*64 + wave*16 + l15) * 64 + quad*8;
    f16x8 wr0 = *(const f16x8*)&Whr[wb];
    f16x8 wr1 = *(const f16x8*)&Whr[wb + 32];
    f16x8 wi0 = *(const f16x8*)&Whi[wb];
    f16x8 wi1 = *(const f16x8*)&Whi[wb + 32];
    f16x8 xr0 = *(const f16x8*)&Xr[l15][quad*8];
    f16x8 xr1 = *(const f16x8*)&Xr[l15][32 + quad*8];
    f16x8 xi0 = *(const f16x8*)&Xi[l15][quad*8];
    f16x8 xi1 = *(const f16x8*)&Xi[l15][32 + quad*8];
    f16x8 xn0, xn1;
    #pragma unroll
    for (int j = 0; j < 8; j++) { xn0[j] = -xi0[j]; xn1[j] = -xi1[j]; }
    f32x4 cr = {0.f,0.f,0.f,0.f}, ci = {0.f,0.f,0.f,0.f};
    cr = __builtin_amdgcn_mfma_f32_16x16x32_f16(xr0, wr0, cr, 0, 0, 0);
    cr = __builtin_amdgcn_mfma_f32_16x16x32_f16(xr1, wr1, cr, 0, 0, 0);
    cr = __builtin_amdgcn_mfma_f32_16x16x32_f16(xn0, wi0, cr, 0, 0, 0);
    cr = __builtin_amdgcn_mfma_f32_16x16x32_f16(xn1, wi1, cr, 0, 0, 0);
    ci = __builtin_amdgcn_mfma_f32_16x16x32_f16(xr0, wi0, ci, 0, 0, 0);
    ci = __builtin_amdgcn_mfma_f32_16x16x32_f16(xr1, wi1, ci, 0, 0, 0);
    ci = __builtin_amdgcn_mfma_f32_16x16x32_f16(xi0, wr0, ci, 0, 0, 0);
    ci = __builtin_amdgcn_mfma_f32_16x16x32_f16(xi1, wr1, ci, 0, 0, 0);
    #pragma unroll
    for (int r = 0; r < 4; r++) {
        int b = bo + quad*4 + r;
        int o = wave*16 + l15;
        ofhr[(size_t)mode*4096 + b*64 + o] = (_Float16)cr[r];
        ofhi[(size_t)mode*4096 + b*64 + o] = (_Float16)ci[r];
    }
}

// ---------------- sG: inverse-x as MFMA GEMM ----------------
// Gh layout [b][x=128][t=24][o=64]; ofh staging vectorized (f16x8, 16B loads)
__global__ __launch_bounds__(256) void k_sG(const _Float16* __restrict__ ofhr, const _Float16* __restrict__ ofhi,
                    const _Float16* __restrict__ T2eT_g, _Float16* __restrict__ Gh) {
    __shared__ _Float16 As[64][72];
    __shared__ _Float16 Cs[128][72];
    int b = blockIdx.x, t = blockIdx.y;
    int tid = threadIdx.x;
    int wave = tid >> 6, lane = tid & 63;
    int l15 = lane & 15, quad = lane >> 4;
    int ky = (t < 12) ? t : (t - 12);
    float sc = ((ky == 0) ? 1.f : 2.f) * (1.f/16384.f);
    bool isReal = (t < 12);
    if (tid < 192) {
        int kxi = tid >> 3, seg = tid & 7;
        size_t idx = (size_t)(kxi*12 + ky)*4096 + b*64 + seg*8;
        f16x8 vr8 = *(const f16x8*)&ofhr[idx];
        f16x8 vi8 = *(const f16x8*)&ofhi[idx];
        #pragma unroll
        for (int j = 0; j < 8; j++) {
            int o = seg*8 + j;
            float vr = (float)vr8[j] * sc, vi = (float)vi8[j] * sc;
            As[o][kxi]      = (_Float16)(isReal ? vr : vi);
            As[o][24 + kxi] = (_Float16)(isReal ? -vi : vr);
        }
    }
    for (int i = tid; i < 1024; i += 256)
        As[i >> 4][48 + (i & 15)] = (_Float16)0.f;
    __syncthreads();
    f16x8 a0 = *(const f16x8*)&As[wave*16 + l15][quad*8];
    f16x8 a1 = *(const f16x8*)&As[wave*16 + l15][32 + quad*8];
    #pragma unroll
    for (int nt = 0; nt < 8; nt++) {
        f16x8 b0 = *(const f16x8*)&T2eT_g[(nt*16 + l15)*64 + quad*8];
        f16x8 b1 = *(const f16x8*)&T2eT_g[(nt*16 + l15)*64 + 32 + quad*8];
        f32x4 acc = {0.f,0.f,0.f,0.f};
        acc = __builtin_amdgcn_mfma_f32_16x16x32_f16(a0, b0, acc, 0, 0, 0);
        acc = __builtin_amdgcn_mfma_f32_16x16x32_f16(a1, b1, acc, 0, 0, 0);
        f16x4 pk;
        #pragma unroll
        for (int r = 0; r < 4; r++) pk[r] = (_Float16)acc[r];
        *(f16x4*)&Cs[nt*16 + l15][wave*16 + quad*4] = pk;
    }
    __syncthreads();
    // write Gh[b][x][t][o]: 128 B contiguous per x (full sectors), stride 3 KB
    float4* o4 = (float4*)Gh;
    for (int i = tid; i < 1024; i += 256) {
        int x = i >> 3, seg = i & 7;
        o4[((size_t)((b*128 + x)*24 + t))*8 + seg] = *(const float4*)&Cs[x][seg*8];
    }
}

// ---------------- S45: fused [pointwise | inverse-y] MFMA + gelu + y-DFT ----------------
// 2 rows/block; G-frags direct from global; stage-A results staged through LDS
// (reusing BsT) then written as contiguous 3 KB float4 blocks (no 2B scatter RMW).
__global__ __launch_bounds__(256, 4) void k_s45(_Float16* __restrict__ xh,
                    const _Float16* __restrict__ Gh,
                    const _Float16* __restrict__ T1e_g, const _Float16* __restrict__ T1eT_g,
                    const _Float16* __restrict__ PWh,
                    const float* __restrict__ pwb,
                    _Float16* __restrict__ Yg, int layer,
                    const float* __restrict__ xyt, const int* __restrict__ Lx,
                    const float* __restrict__ val, const float* __restrict__ cnt,
                    const float* __restrict__ xg, const float* __restrict__ yg,
                    const float* __restrict__ fc0w, const float* __restrict__ fc0b) {
    __shared__ _Float16 BsT[2][128][76];   // [row-in-pair][y][c]; x -> post-gelu -> Yl staging
    __shared__ float wl[4][64];
    int rp = blockIdx.x, b = blockIdx.y;
    int row0 = rp << 1;
    int tid = threadIdx.x;
    int wave = tid >> 6, lane = tid & 63;
    int l15 = lane & 15, quad = lane >> 4;

    // G fragments direct from global, issued first (t = quad*8+j < 24 -> quad<3)
    f16x8 af2[2];
    #pragma unroll
    for (int r2 = 0; r2 < 2; r2++)
        #pragma unroll
        for (int j = 0; j < 8; j++) af2[r2][j] = (_Float16)0.f;
    if (quad < 3) {
        #pragma unroll
        for (int r2 = 0; r2 < 2; r2++) {
            const _Float16* gt = Gh + (size_t)(b*128 + row0 + r2) * 1536 + wave*16 + l15;
            #pragma unroll
            for (int j = 0; j < 8; j++) af2[r2][j] = gt[(quad*8 + j) * 64];
        }
    }

    // hoisted operand loads (shared across both rows)
    f16x8 af0 = *(const f16x8*)&PWh[(size_t)(layer*64 + wave*16 + l15)*64 + quad*8];
    f16x8 af1 = *(const f16x8*)&PWh[(size_t)(layer*64 + wave*16 + l15)*64 + 32 + quad*8];
    f16x8 b2a[8];
    #pragma unroll
    for (int nt = 0; nt < 8; nt++)
        b2a[nt] = *(const f16x8*)&T1eT_g[(nt*16 + l15)*32 + quad*8];
    float pb[4];
    #pragma unroll
    for (int r = 0; r < 4; r++)
        pb[r] = pwb[layer*64 + wave*16 + quad*4 + r];

    // x tile fill (both rows): layer 0 recomputes fc0; others load from xh
    if (layer == 0) {
        if (tid < 64) {
            wl[0][tid] = fc0w[tid]; wl[1][tid] = fc0w[64+tid];
            wl[2][tid] = fc0w[128+tid]; wl[3][tid] = fc0b[tid];
        }
        __syncthreads();
        int y = tid & 127, half = tid >> 7;
        #pragma unroll
        for (int r2 = 0; r2 < 2; r2++) {
            int p = (row0 + r2)*128 + y;
            float c = cnt[(size_t)b*Pg + p];
            float g = (c > 0.f) ? val[(size_t)b*Pg + p] / fmaxf(c, 1e-6f) : 0.f;
            float a1 = xg[p], a2 = yg[p];
            #pragma unroll
            for (int blk = 0; blk < 4; blk++) {
                f16x8 pkk;
                #pragma unroll
                for (int j = 0; j < 8; j++) {
                    int o = half*32 + blk*8 + j;
                    pkk[j] = (_Float16)(g*wl[0][o] + a1*wl[1][o] + a2*wl[2][o] + wl[3][o]);
                }
                *(f16x8*)&BsT[r2][y][half*32 + blk*8] = pkk;
            }
        }
    } else {
        for (int i = tid; i < 2048; i += 256) {
            int r2 = i >> 10, k = i & 1023;
            int y = k >> 3, seg = k & 7;
            *(float4*)&BsT[r2][y][seg*8] =
                ((const float4*)(xh + (size_t)(b*128 + row0 + r2) * 8192))[k];
        }
    }
    __syncthreads();

    // per-row MFMA + gelu into registers (acc reused across rows)
    f16x4 pk[2][8];
    #pragma unroll
    for (int r2 = 0; r2 < 2; r2++) {
        f32x4 acc[8];
        #pragma unroll
        for (int nt = 0; nt < 8; nt++) {
            f32x4 a = {0.f,0.f,0.f,0.f};
            f16x8 b0 = *(const f16x8*)&BsT[r2][nt*16 + l15][quad*8];
            f16x8 b1 = *(const f16x8*)&BsT[r2][nt*16 + l15][32 + quad*8];
            a = __builtin_amdgcn_mfma_f32_16x16x32_f16(af0, b0, a, 0, 0, 0);
            a = __builtin_amdgcn_mfma_f32_16x16x32_f16(af1, b1, a, 0, 0, 0);
            a = __builtin_amdgcn_mfma_f32_16x16x32_f16(af2[r2], b2a[nt], a, 0, 0, 0);
            acc[nt] = a;
        }
        #pragma unroll
        for (int nt = 0; nt < 8; nt++)
            #pragma unroll
            for (int r = 0; r < 4; r++)
                pk[r2][nt][r] = (_Float16)fast_gelu(acc[nt][r] + pb[r]);
    }
    __syncthreads();   // all BsT reads complete before overwrite

    // write gelu outputs into BsT
    #pragma unroll
    for (int r2 = 0; r2 < 2; r2++)
        #pragma unroll
        for (int nt = 0; nt < 8; nt++)
            *(f16x4*)&BsT[r2][nt*16 + l15][wave*16 + quad*4] = pk[r2][nt];
    __syncthreads();

    // x store (layer 2: only the two rows k_final will read)
    bool st0 = true, st1 = true;
    if (layer == 2) {
        float Lxf = fmaxf((float)Lx[0], 1e-6f);
        float x01 = fminf(fmaxf(xyt[b*3 + 0] / Lxf, 0.f), 1.f);
        float gxp = x01 * (NXg - 1);
        int x0 = (int)floorf(gxp);
        int x1 = min(x0 + 1, NXg - 1);
        st0 = (row0 == x0) || (row0 == x1);
        st1 = (row0 + 1 == x0) || (row0 + 1 == x1);
    }
    for (int i = tid; i < 2048; i += 256) {
        int r2 = i >> 10, k = i & 1023;
        if (r2 ? st1 : st0) {
            int y = k >> 3, seg = k & 7;
            ((float4*)(xh + (size_t)(b*128 + row0 + r2) * 8192))[k] =
                *(const float4*)&BsT[r2][y][seg*8];
        }
    }

    // stage-A for both rows: load fragments, then reuse BsT[0] as Yl[2][64][24]
    f16x8 bf[8];
    stageA_bf(T1e_g, lane, bf);
    f16x8 afA[4], afB[4];
    stageA_af(BsT[0], tid, afA);
    stageA_af(BsT[1], tid, afB);
    __syncthreads();                        // all BsT reads done before reuse
    _Float16* Yl = &BsT[0][0][0];           // 2*1536 halves = 6 KB inside BsT[0]
    stageA_lds(afA, bf, Yl, tid);
    stageA_lds(afB, bf, Yl + 1536, tid);
    __syncthreads();
    for (int i = tid; i < 384; i += 256) {
        int r2 = i >= 192;
        int j = i - r2*192;
        ((float4*)(Yg + (size_t)(b*128 + row0 + r2) * 1536))[j] =
            ((const float4*)(Yl + r2*1536))[j];
    }
}

// ---------------- final: layer-3 at 4 points + fc1 + fc2 + bilinear ----------------
__global__ __launch_bounds__(256) void k_final(const _Float16* __restrict__ x,
                    const _Float16* __restrict__ ofhr, const _Float16* __restrict__ ofhi,
                    const float* __restrict__ pw, const float* __restrict__ pwb,
                    const float* __restrict__ fc1w, const float* __restrict__ fc1b,
                    const float* __restrict__ fc2w, const float* __restrict__ fc2b,
                    const float* __restrict__ xyt, const int* __restrict__ Lx, const int* __restrict__ Ly,
                    const float* __restrict__ Tc, const float* __restrict__ Ts,
                    float* __restrict__ out) {
    __shared__ float y4[4][64];
    __shared__ float hh[4][129];
    __shared__ int   pxy[4][2];
    __shared__ float wxy[2];
    __shared__ float tc[128], ts[128];
    int b = blockIdx.x;
    if (threadIdx.x < 128) {
        tc[threadIdx.x] = Tc[threadIdx.x];
        ts[threadIdx.x] = Ts[threadIdx.x];
    }
    if (threadIdx.x == 0) {
        float Lxf = fmaxf((float)Lx[0], 1e-6f);
        float Lyf = fmaxf((float)Ly[0], 1e-6f);
        float x01 = fminf(fmaxf(xyt[b*3 + 0] / Lxf, 0.f), 1.f);
        float y01 = fminf(fmaxf(xyt[b*3 + 1] / Lyf, 0.f), 1.f);
        float gx = x01 * (NXg - 1), gy = y01 * (NYg - 1);
        int x0 = (int)floorf(gx), y0 = (int)floorf(gy);
        int x1 = min(x0 + 1, NXg - 1), y1 = min(y0 + 1, NYg - 1);
        wxy[0] = gx - (float)x0;
        wxy[1] = gy - (float)y0;
        pxy[0][0] = x0; pxy[0][1] = y0;
        pxy[1][0] = x1; pxy[1][1] = y0;
        pxy[2][0] = x0; pxy[2][1] = y1;
        pxy[3][0] = x1; pxy[3][1] = y1;
    }
    __syncthreads();
    {
        int p = threadIdx.x >> 6, o = threadIdx.x & 63;
        int px = pxy[p][0], py = pxy[p][1];
        float gkr[12], gki[12];
        #pragma unroll
        for (int ky = 0; ky < 12; ky++) { gkr[ky] = 0.f; gki[ky] = 0.f; }
        for (int kxi = 0; kxi < 24; kxi++) {
            int kx = (kxi < 12) ? kxi : (104 + kxi);
            int m = (kx * px) & 127;
            float cc = tc[m], ss = ts[m];
            #pragma unroll
            for (int ky = 0; ky < 12; ky++) {
                size_t idx = (size_t)(kxi*12 + ky)*4096 + b*64 + o;
                float a = (float)ofhr[idx], bb = (float)ofhi[idx];
                gkr[ky] += a*cc - bb*ss;
                gki[ky] += a*ss + bb*cc;
            }
        }
        float sp = gkr[0];
        #pragma unroll
        for (int ky = 1; ky < 12; ky++) {
            int m = (ky * py) & 127;
            sp += 2.f * (gkr[ky]*tc[m] - gki[ky]*ts[m]);
        }
        float s = 0.f;
        const _Float16* xb = x + ((size_t)(b*128 + px)*128 + py)*64;
        #pragma unroll 4
        for (int c = 0; c < 64; c++)
            s += pw[3*4096 + o*64 + c] * (float)xb[c];
        y4[p][o] = sp * (1.f/16384.f) + s + pwb[3*64 + o];
    }
    __syncthreads();
    for (int i = threadIdx.x; i < 512; i += 256) {
        int p = i >> 7, f = i & 127;
        float s = fc1b[f];
        #pragma unroll 4
        for (int w = 0; w < 64; w++) s += y4[p][w] * fc1w[w*128 + f];
        hh[p][f] = 0.5f * s * (1.f + erff(s * 0.70710678118654752f));
    }
    __syncthreads();
    if (threadIdx.x < 3) {
        int o3 = threadIdx.x;
        float f4[4];
        #pragma unroll
        for (int p = 0; p < 4; p++) {
            float s = fc2b[o3];
            #pragma unroll 4
            for (int f = 0; f < 128; f++) s += hh[p][f] * fc2w[f*3 + o3];
            f4[p] = s;
        }
        float wx = wxy[0], wy = wxy[1];
        float top = f4[0]*(1.f - wx) + f4[1]*wx;
        float bot = f4[2]*(1.f - wx) + f4[3]*wx;
        out[b*3 + o3] = top*(1.f - wy) + bot*wy;
    }
}

extern "C" void kernel_launch(void* const* d_in, const int* in_sizes, int n_in,
                              void* d_out, int out_size, void* d_ws, size_t ws_size,
                              hipStream_t stream) {
    const float* xyt    = (const float*)d_in[0];
    const float* obs_c  = (const float*)d_in[1];
    const float* obs_v  = (const float*)d_in[2];
    const float* xg     = (const float*)d_in[3];
    const float* yg     = (const float*)d_in[4];
    const float* fc0w   = (const float*)d_in[5];
    const float* fc0b   = (const float*)d_in[6];
    const float* w1r    = (const float*)d_in[7];
    const float* w1i    = (const float*)d_in[8];
    const float* w2r    = (const float*)d_in[9];
    const float* w2i    = (const float*)d_in[10];
    const float* pww    = (const float*)d_in[11];
    const float* pwb    = (const float*)d_in[12];
    const float* fc1w   = (const float*)d_in[13];
    const float* fc1b   = (const float*)d_in[14];
    const float* fc2w   = (const float*)d_in[15];
    const float* fc2b   = (const float*)d_in[16];
    const int*   nb     = (const int*)d_in[17];
    const int*   siy    = (const int*)d_in[18];
    const int*   six    = (const int*)d_in[19];
    const int*   Lx     = (const int*)d_in[20];
    const int*   Ly     = (const int*)d_in[21];
    float* out = (float*)d_out;

    float* W = (float*)d_ws;
    float* Tc  = W + OFF_TC;
    float* Ts  = W + OFF_TS;
    _Float16* Hbase = (_Float16*)(W + F32_END);
    _Float16* T1e_g  = Hbase + H_T1E;
    _Float16* T1eT_g = Hbase + H_T1ET;
    _Float16* A2_g   = Hbase + H_A2;
    _Float16* PWh    = Hbase + H_PWH;
    _Float16* T2eT_g = Hbase + H_T2ET;
    _Float16* xfhr   = Hbase + H_XFHR;
    _Float16* xfhi   = Hbase + H_XFHI;
    _Float16* ofhr   = Hbase + H_OFHR;
    _Float16* ofhi   = Hbase + H_OFHI;
    _Float16* Whr    = Hbase + H_WHR;
    _Float16* Whi    = Hbase + H_WHI;
    _Float16* Yg     = Hbase + H_YG;
    _Float16* xh     = Hbase + H_X;
    float*    val    = (float*)(Hbase + H_U);
    float*    cnt    = val + Bq*Pg;
    _Float16* Gh2    = Hbase + H_U + (size_t)4*Bq*Pg;   // after val/cnt (no alias)

    hipMemsetAsync(val, 0, (size_t)2 * Bq * Pg * sizeof(float), stream);

    k_prep<<<1104, 256, 0, stream>>>(T1e_g, T1eT_g, A2_g, pww, PWh, T2eT_g, Tc, Ts,
                                     xyt, obs_c, obs_v, nb, siy, six, val, cnt,
                                     w1r, w1i, w2r, w2i, Whr, Whi);
    k_fc0y<<<dim3(128, Bq), 256, 0, stream>>>(val, cnt, xg, yg, fc0w, fc0b, T1e_g, Yg);

    for (int l = 0; l < 3; l++) {
        k_sB<<<Bq*Wd/4, 256, 0, stream>>>(Yg, A2_g, xfhr, xfhi);
        k_s3m<<<dim3(288, 4), 256, 0, stream>>>(xfhr, xfhi, Whr, Whi, ofhr, ofhi, l);
        k_sG<<<dim3(Bq, 24), 256, 0, stream>>>(ofhr, ofhi, T2eT_g, Gh2);
        k_s45<<<dim3(64, Bq), 256, 0, stream>>>(xh, Gh2, T1e_g, T1eT_g, PWh, pwb, Yg, l,
                                                xyt, Lx, val, cnt, xg, yg, fc0w, fc0b);
    }
    // layer 3: spectral coefficients (MFMA path) + k_final
    k_sB<<<Bq*Wd/4, 256, 0, stream>>>(Yg, A2_g, xfhr, xfhi);
    k_s3m<<<dim3(288, 4), 256, 0, stream>>>(xfhr, xfhi, Whr, Whi, ofhr, ofhi, 3);
    k_final<<<Bq, 256, 0, stream>>>(xh, ofhr, ofhi, pww, pwb, fc1w, fc1b, fc2w, fc2b,
                                    xyt, Lx, Ly, Tc, Ts, out);
}

// Round 9
// 610.349 us; speedup vs baseline: 1.0135x; 1.0135x over previous
//
#include <hip/hip_runtime.h>
#include <math.h>

// Problem constants
#define NXg 128
#define NYg 128
#define Pg  (NXg*NYg)      // 16384 pixels
#define Bq  64             // batch
#define Wd  64             // WIDTH (channels)
#define NKX 24             // kept kx rows: 0..11 and 116..127
#define NMODE (NKX*12)     // 288
#define PI2_128 0.04908738521234052f   // 2*pi/128

typedef _Float16 f16x8 __attribute__((ext_vector_type(8)));
typedef _Float16 f16x4 __attribute__((ext_vector_type(4)));
typedef float    f32x4 __attribute__((ext_vector_type(4)));

// ---------------- workspace layout ----------------
#define OFF_TC  0
#define OFF_TS  (OFF_TC + 128)
#define F32_END (OFF_TS + 128)
#define H_T1E  0                          // T1e  [t=32][y=128]
#define H_T1ET (H_T1E + 32*128)           // T1eT [y=128][t=32]
#define H_A2   (H_T1ET + 128*32)          // A2   [48][256]
#define H_PWH  (H_A2 + 48*256)            // PWh  [4][64][64]
#define H_T2ET (H_PWH + 4*64*64)          // T2eT [x=128][k=64]
#define H_XFHR (H_T2ET + 128*64)          // xfh  [mode=288][bc=4096] fp16
#define H_XFHI (H_XFHR + 288*4096)
#define H_OFHR (H_XFHI + 288*4096)        // ofh  [mode][bc] fp16
#define H_OFHI (H_OFHR + 288*4096)
#define H_WHR  (H_OFHI + 288*4096)        // Wh   [4][288][o=64][i=64] fp16
#define H_WHI  (H_WHR + (size_t)4*288*4096)
#define H_YG   (H_WHI + (size_t)4*288*4096)       // Yg [b][row][o][t=24]  (contiguous 3KB per (b,row))
#define H_X    (H_YG + (size_t)Bq*Wd*128*24)      // x  [b][x][y][c]
#define H_U    (H_X + (size_t)Bq*128*128*64)      // union: val/cnt | Gh

// ---------------- fast gelu: 0.5*v*(1+erf(v/sqrt2)), A&S 7.1.26 erf ----------------
__device__ __forceinline__ float fast_gelu(float v) {
    float a = fabsf(v) * 0.70710678118654752f;
    float t = 1.f / (1.f + 0.3275911f * a);
    float p = t * (0.254829592f + t * (-0.284496736f + t * (1.421413741f +
              t * (-1.453152027f + t * 1.061405429f))));
    float er = 1.f - p * __expf(-a * a);
    er = copysignf(er, v);
    return 0.5f * v * (1.f + er);
}

// ---------------- prep: tables + scatter + coalesced Wh transpose ----------------
// grid 1104 blocks x 256: blk<64 tables; 64..79 scatter; 80..1103 Wh transpose
__global__ void k_prep(_Float16* T1e_g, _Float16* T1eT_g, _Float16* A2_g,
                       const float* pww, _Float16* PWh, _Float16* T2eT_g,
                       float* Tc, float* Ts,
                       const float* xyt, const float* obs_c, const float* obs_v,
                       const int* nb, const int* siy, const int* six,
                       float* val, float* cnt,
                       const float* w1r, const float* w1i,
                       const float* w2r, const float* w2i,
                       _Float16* Whr, _Float16* Whi) {
    __shared__ _Float16 L[64][146];   // transpose tile; pad 146 -> conflict-free col reads
    int blk = blockIdx.x;
    if (blk < 64) {
        int t = blk * 256 + threadIdx.x;   // 0..16383
        if (t < 32*128) {
            int r = t >> 7, y = t & 127;
            float v = 0.f;
            if (r < 12)      v =  cosf((float)((r * y) & 127) * PI2_128);
            else if (r < 24) v = -sinf((float)(((r-12) * y) & 127) * PI2_128);
            T1e_g[t] = (_Float16)v;
            int y2 = t >> 5, r2 = t & 31;
            float v2 = 0.f;
            if (r2 < 12)      v2 =  cosf((float)((r2 * y2) & 127) * PI2_128);
            else if (r2 < 24) v2 = -sinf((float)(((r2-12) * y2) & 127) * PI2_128);
            T1eT_g[t] = (_Float16)v2;
        }
        if (t < 48*256) {
            int m = t >> 8, k = t & 255;
            int x = k & 127;
            int hi = (k >= 128);
            float v;
            if (m < 24) {
                int kx = (m < 12) ? m : (104 + m);
                float th = (float)((kx * x) & 127) * PI2_128;
                v = hi ? sinf(th) : cosf(th);
            } else {
                int mm = m - 24;
                int kx = (mm < 12) ? mm : (104 + mm);
                float th = (float)((kx * x) & 127) * PI2_128;
                v = hi ? cosf(th) : -sinf(th);
            }
            A2_g[t] = (_Float16)v;
        }
        if (t < 4*64*64) PWh[t] = (_Float16)pww[t];
        if (t < 128*64) {
            int x = t >> 6, k = t & 63;
            float v = 0.f;
            if (k < 24) {
                int kx = (k < 12) ? k : (104 + k);
                v = cosf((float)((kx * x) & 127) * PI2_128);
            } else if (k < 48) {
                int kk = k - 24;
                int kx = (kk < 12) ? kk : (104 + kk);
                v = sinf((float)((kx * x) & 127) * PI2_128);
            }
            T2eT_g[t] = (_Float16)v;
        }
        if (t < 128) {
            float th = (float)t * PI2_128;
            Tc[t] = cosf(th);
            Ts[t] = sinf(th);
        }
    } else if (blk < 80) {
        int t = (blk - 64) * 256 + threadIdx.x;   // 0..4095 = B*K
        int b = t >> 6;
        int id = nb[t];
        int sid = id / 50;                        // NT = 50
        float tq = xyt[b*3 + 2];
        float w = expf(-0.1f * fabsf(obs_c[id*3 + 2] - tq));
        int lin = siy[sid] * NYg + six[sid];
        atomicAdd(&val[b*Pg + lin], obs_v[id] * w);
        atomicAdd(&cnt[b*Pg + lin], w);
    } else {
        // coalesced Wh transpose: src [layer][i=64][o=64][m=144] f32 (contiguous m)
        //                         dst Wh[(layer*288 + half*144 + m)*4096 + o*64 + i]
        int u = blk - 80;                 // 0..1023
        int layer = u >> 8;
        int rem = u & 255;
        int o = rem & 63, ri = (rem >> 6) & 1, half = rem >> 7;
        const float* src = half ? (ri ? w2i : w2r) : (ri ? w1i : w1r);
        _Float16* dst = ri ? Whi : Whr;
        size_t sbase = (size_t)layer * 589824 + (size_t)o * 144;
        for (int idx = threadIdx.x; idx < 9216; idx += 256) {
            int i = idx / 144, m = idx - i*144;
            L[i][m] = (_Float16)src[sbase + (size_t)i*9216 + m];
        }
        __syncthreads();
        size_t obase = ((size_t)(layer*288 + half*144) << 12) + o*64;
        for (int idx = threadIdx.x; idx < 9216; idx += 256) {
            int m = idx >> 6, i = idx & 63;
            dst[obase + ((size_t)m << 12) + i] = L[i][m];
        }
    }
}

// ---------------- stage-A y-DFT epilogue ----------------
__device__ __forceinline__ void stageA_bf(const _Float16* __restrict__ T1e_g, int lane, f16x8* bf) {
    int l15 = lane & 15, quad = lane >> 4;
    #pragma unroll
    for (int u = 0; u < 8; u++) {
        int nt2 = u >> 2, q = u & 3;
        bf[u] = *(const f16x8*)&T1e_g[(nt2*16 + l15)*128 + q*32 + quad*8];
    }
}

// direct-scatter store to Yg[b][row][o][t]: per instr, 16 lanes write 32 B runs
// of consecutive t (L2 merges to full sectors -- proven non-amplifying, r6/r8)
__device__ __forceinline__ void stageA_core(const _Float16 (*Xn)[76], const f16x8* bf,
                                            _Float16* __restrict__ Yg, int b, int row, int tid) {
    int wave = tid >> 6, lane = tid & 63;
    int l15 = lane & 15, quad = lane >> 4;
    f16x8 af[4];
    #pragma unroll
    for (int q = 0; q < 4; q++)
        #pragma unroll
        for (int j = 0; j < 8; j++)
            af[q][j] = Xn[q*32 + quad*8 + j][wave*16 + l15];
    _Float16* yrow = Yg + (size_t)(b*128 + row) * 1536;
    #pragma unroll
    for (int nt2 = 0; nt2 < 2; nt2++) {
        f32x4 acc = {0.f,0.f,0.f,0.f};
        #pragma unroll
        for (int q = 0; q < 4; q++)
            acc = __builtin_amdgcn_mfma_f32_16x16x32_f16(af[q], bf[nt2*4 + q], acc, 0, 0, 0);
        int t = nt2*16 + l15;
        if (t < 24) {
            #pragma unroll
            for (int r = 0; r < 4; r++)
                yrow[(wave*16 + quad*4 + r)*24 + t] = (_Float16)acc[r];
        }
    }
}

__device__ __forceinline__ void stageA(const _Float16 (*Xn)[76], const _Float16* __restrict__ T1e_g,
                                       _Float16* __restrict__ Yg, int b, int row, int tid) {
    f16x8 bf[8];
    stageA_bf(T1e_g, tid & 63, bf);
    stageA_core(Xn, bf, Yg, b, row, tid);
}

// ---------------- fc0-lite: compute fc0 + stage-A only ----------------
__global__ __launch_bounds__(256) void k_fc0y(const float* __restrict__ val, const float* __restrict__ cnt,
                      const float* __restrict__ xg, const float* __restrict__ yg,
                      const float* __restrict__ w, const float* __restrict__ bb,
                      const _Float16* __restrict__ T1e_g,
                      _Float16* __restrict__ Yg) {
    __shared__ _Float16 Xn[128][76];
    __shared__ float wl[4][64];
    int row = blockIdx.x, b = blockIdx.y;
    int tid = threadIdx.x;
    if (tid < 64) {
        wl[0][tid] = w[tid]; wl[1][tid] = w[64+tid]; wl[2][tid] = w[128+tid]; wl[3][tid] = bb[tid];
    }
    __syncthreads();
    {
        int y = tid & 127, half = tid >> 7;
        int p = row*128 + y;
        float c = cnt[(size_t)b*Pg + p];
        float g = (c > 0.f) ? val[(size_t)b*Pg + p] / fmaxf(c, 1e-6f) : 0.f;
        float a1 = xg[p], a2 = yg[p];
        #pragma unroll
        for (int blk = 0; blk < 4; blk++) {
            f16x8 pk;
            #pragma unroll
            for (int j = 0; j < 8; j++) {
                int o = half*32 + blk*8 + j;
                pk[j] = (_Float16)(g*wl[0][o] + a1*wl[1][o] + a2*wl[2][o] + wl[3][o]);
            }
            *(f16x8*)&Xn[y][half*32 + blk*8] = pk;
        }
    }
    __syncthreads();
    stageA(Xn, T1e_g, Yg, b, row, tid);
}

// ---------------- sB: stage-B x-DFT via MFMA, 4 bc per block ----------------
// grid 1024 x 256. Wave w computes bc = 4*blk + w over 3 m-tiles.
// Yg layout [b][x][o][t=24]: block's 4 c are consecutive within one b ->
// 96 contiguous elems (192 B) per x.
__global__ __launch_bounds__(256) void k_sB(const _Float16* __restrict__ Yg,
                    const _Float16* __restrict__ A2_g,
                    _Float16* __restrict__ xfhr, _Float16* __restrict__ xfhi) {
    __shared__ _Float16 Ys[4][28][136];
    int bc4 = blockIdx.x << 2;
    int tid = threadIdx.x;
    int wave = tid >> 6, lane = tid & 63;
    int l15 = lane & 15, quad = lane >> 4;
    int b = bc4 >> 6, c0 = bc4 & 63;
    const _Float16* base = Yg + ((size_t)b*128*64 + c0)*24;   // + x*1536
    for (int i = tid; i < 1536; i += 256) {
        int x = i / 12, w = i - x*12;
        f16x8 v = *(const f16x8*)&base[(size_t)x*1536 + w*8];
        int e = w*8;
        #pragma unroll
        for (int j = 0; j < 8; j++) {
            int tt = e + j;                // 0..95
            int s = tt / 24, t = tt - s*24;
            Ys[s][t][x] = v[j];
        }
    }
    __syncthreads();
    int bc = bc4 + wave;
    #pragma unroll
    for (int mt = 0; mt < 3; mt++) {
        f32x4 acc = {0.f,0.f,0.f,0.f};
        #pragma unroll
        for (int q = 0; q < 8; q++) {
            f16x8 a = *(const f16x8*)&A2_g[(size_t)(mt*16 + l15)*256 + q*32 + quad*8];
            const _Float16* brow = (q < 4) ? &Ys[wave][l15][q*32 + quad*8]
                                           : &Ys[wave][12 + l15][(q-4)*32 + quad*8];
            f16x8 bfr = *(const f16x8*)brow;
            acc = __builtin_amdgcn_mfma_f32_16x16x32_f16(a, bfr, acc, 0, 0, 0);
        }
        if (l15 < 12) {
            #pragma unroll
            for (int r = 0; r < 4; r++) {
                int m = mt*16 + quad*4 + r;
                if (m < 24) xfhr[(size_t)(m*12 + l15)*4096 + bc] = (_Float16)acc[r];
                else        xfhi[(size_t)((m-24)*12 + l15)*4096 + bc] = (_Float16)acc[r];
            }
        }
    }
}

// ---------------- s3m: mode mixing via MFMA, 4-way batch split ----------------
__global__ __launch_bounds__(256) void k_s3m(const _Float16* __restrict__ xfhr, const _Float16* __restrict__ xfhi,
                    const _Float16* __restrict__ Whr, const _Float16* __restrict__ Whi,
                    _Float16* __restrict__ ofhr, _Float16* __restrict__ ofhi, int layer) {
    __shared__ _Float16 Xr[16][72], Xi[16][72];
    int mode = blockIdx.x;
    int bo = blockIdx.y << 4;          // batch offset: 0,16,32,48
    int tid = threadIdx.x;
    int wave = tid >> 6, lane = tid & 63;
    int l15 = lane & 15, quad = lane >> 4;
    const _Float16* pr = xfhr + (size_t)mode * 4096 + bo*64;
    const _Float16* pi = xfhi + (size_t)mode * 4096 + bo*64;
    if (tid < 128) {
        int b = tid >> 3, seg = tid & 7;
        *(f16x8*)&Xr[b][seg*8] = *(const f16x8*)&pr[tid*8];
        *(f16x8*)&Xi[b][seg*8] = *(const f16x8*)&pi[tid*8];
    }
    __syncthreads();
    size_t wb = ((size_t)(layer*288 + mode)*64 + wave*16 + l15) * 64 + quad*8;
    f16x8 wr0 = *(const f16x8*)&Whr[wb];
    f16x8 wr1 = *(const f16x8*)&Whr[wb + 32];
    f16x8 wi0 = *(const f16x8*)&Whi[wb];
    f16x8 wi1 = *(const f16x8*)&Whi[wb + 32];
    f16x8 xr0 = *(const f16x8*)&Xr[l15][quad*8];
    f16x8 xr1 = *(const f16x8*)&Xr[l15][32 + quad*8];
    f16x8 xi0 = *(const f16x8*)&Xi[l15][quad*8];
    f16x8 xi1 = *(const f16x8*)&Xi[l15][32 + quad*8];
    f16x8 xn0, xn1;
    #pragma unroll
    for (int j = 0; j < 8; j++) { xn0[j] = -xi0[j]; xn1[j] = -xi1[j]; }
    f32x4 cr = {0.f,0.f,0.f,0.f}, ci = {0.f,0.f,0.f,0.f};
    cr = __builtin_amdgcn_mfma_f32_16x16x32_f16(xr0, wr0, cr, 0, 0, 0);
    cr = __builtin_amdgcn_mfma_f32_16x16x32_f16(xr1, wr1, cr, 0, 0, 0);
    cr = __builtin_amdgcn_mfma_f32_16x16x32_f16(xn0, wi0, cr, 0, 0, 0);
    cr = __builtin_amdgcn_mfma_f32_16x16x32_f16(xn1, wi1, cr, 0, 0, 0);
    ci = __builtin_amdgcn_mfma_f32_16x16x32_f16(xr0, wi0, ci, 0, 0, 0);
    ci = __builtin_amdgcn_mfma_f32_16x16x32_f16(xr1, wi1, ci, 0, 0, 0);
    ci = __builtin_amdgcn_mfma_f32_16x16x32_f16(xi0, wr0, ci, 0, 0, 0);
    ci = __builtin_amdgcn_mfma_f32_16x16x32_f16(xi1, wr1, ci, 0, 0, 0);
    #pragma unroll
    for (int r = 0; r < 4; r++) {
        int b = bo + quad*4 + r;
        int o = wave*16 + l15;
        ofhr[(size_t)mode*4096 + b*64 + o] = (_Float16)cr[r];
        ofhi[(size_t)mode*4096 + b*64 + o] = (_Float16)ci[r];
    }
}

// ---------------- sG: inverse-x as MFMA GEMM ----------------
// Gh layout [b][x=128][t=24][o=64]; ofh staging vectorized (f16x8, 16B loads)
__global__ __launch_bounds__(256) void k_sG(const _Float16* __restrict__ ofhr, const _Float16* __restrict__ ofhi,
                    const _Float16* __restrict__ T2eT_g, _Float16* __restrict__ Gh) {
    __shared__ _Float16 As[64][72];
    __shared__ _Float16 Cs[128][72];
    int b = blockIdx.x, t = blockIdx.y;
    int tid = threadIdx.x;
    int wave = tid >> 6, lane = tid & 63;
    int l15 = lane & 15, quad = lane >> 4;
    int ky = (t < 12) ? t : (t - 12);
    float sc = ((ky == 0) ? 1.f : 2.f) * (1.f/16384.f);
    bool isReal = (t < 12);
    if (tid < 192) {
        int kxi = tid >> 3, seg = tid & 7;
        size_t idx = (size_t)(kxi*12 + ky)*4096 + b*64 + seg*8;
        f16x8 vr8 = *(const f16x8*)&ofhr[idx];
        f16x8 vi8 = *(const f16x8*)&ofhi[idx];
        #pragma unroll
        for (int j = 0; j < 8; j++) {
            int o = seg*8 + j;
            float vr = (float)vr8[j] * sc, vi = (float)vi8[j] * sc;
            As[o][kxi]      = (_Float16)(isReal ? vr : vi);
            As[o][24 + kxi] = (_Float16)(isReal ? -vi : vr);
        }
    }
    for (int i = tid; i < 1024; i += 256)
        As[i >> 4][48 + (i & 15)] = (_Float16)0.f;
    __syncthreads();
    f16x8 a0 = *(const f16x8*)&As[wave*16 + l15][quad*8];
    f16x8 a1 = *(const f16x8*)&As[wave*16 + l15][32 + quad*8];
    #pragma unroll
    for (int nt = 0; nt < 8; nt++) {
        f16x8 b0 = *(const f16x8*)&T2eT_g[(nt*16 + l15)*64 + quad*8];
        f16x8 b1 = *(const f16x8*)&T2eT_g[(nt*16 + l15)*64 + 32 + quad*8];
        f32x4 acc = {0.f,0.f,0.f,0.f};
        acc = __builtin_amdgcn_mfma_f32_16x16x32_f16(a0, b0, acc, 0, 0, 0);
        acc = __builtin_amdgcn_mfma_f32_16x16x32_f16(a1, b1, acc, 0, 0, 0);
        f16x4 pk;
        #pragma unroll
        for (int r = 0; r < 4; r++) pk[r] = (_Float16)acc[r];
        *(f16x4*)&Cs[nt*16 + l15][wave*16 + quad*4] = pk;
    }
    __syncthreads();
    // write Gh[b][x][t][o]: 128 B contiguous per x (full sectors), stride 3 KB
    float4* o4 = (float4*)Gh;
    for (int i = tid; i < 1024; i += 256) {
        int x = i >> 3, seg = i & 7;
        o4[((size_t)((b*128 + x)*24 + t))*8 + seg] = *(const float4*)&Cs[x][seg*8];
    }
}

// ---------------- S45: fused [pointwise | inverse-y] MFMA + gelu + y-DFT ----------------
// 2 rows/block; G-frags direct from global; round-6 epilogue (2 barriers, direct
// Yg scatter -- proven non-amplifying) targeting Yg[b][row][o][t].
__global__ __launch_bounds__(256, 4) void k_s45(_Float16* __restrict__ xh,
                    const _Float16* __restrict__ Gh,
                    const _Float16* __restrict__ T1e_g, const _Float16* __restrict__ T1eT_g,
                    const _Float16* __restrict__ PWh,
                    const float* __restrict__ pwb,
                    _Float16* __restrict__ Yg, int layer,
                    const float* __restrict__ xyt, const int* __restrict__ Lx,
                    const float* __restrict__ val, const float* __restrict__ cnt,
                    const float* __restrict__ xg, const float* __restrict__ yg,
                    const float* __restrict__ fc0w, const float* __restrict__ fc0b) {
    __shared__ _Float16 BsT[2][128][76];   // [row-in-pair][y][c]; holds x then post-gelu
    __shared__ float wl[4][64];
    int rp = blockIdx.x, b = blockIdx.y;
    int row0 = rp << 1;
    int tid = threadIdx.x;
    int wave = tid >> 6, lane = tid & 63;
    int l15 = lane & 15, quad = lane >> 4;

    // G fragments direct from global, issued first (t = quad*8+j < 24 -> quad<3)
    f16x8 af2[2];
    #pragma unroll
    for (int r2 = 0; r2 < 2; r2++)
        #pragma unroll
        for (int j = 0; j < 8; j++) af2[r2][j] = (_Float16)0.f;
    if (quad < 3) {
        #pragma unroll
        for (int r2 = 0; r2 < 2; r2++) {
            const _Float16* gt = Gh + (size_t)(b*128 + row0 + r2) * 1536 + wave*16 + l15;
            #pragma unroll
            for (int j = 0; j < 8; j++) af2[r2][j] = gt[(quad*8 + j) * 64];
        }
    }

    // hoisted operand loads (shared across both rows)
    f16x8 af0 = *(const f16x8*)&PWh[(size_t)(layer*64 + wave*16 + l15)*64 + quad*8];
    f16x8 af1 = *(const f16x8*)&PWh[(size_t)(layer*64 + wave*16 + l15)*64 + 32 + quad*8];
    f16x8 b2a[8];
    #pragma unroll
    for (int nt = 0; nt < 8; nt++)
        b2a[nt] = *(const f16x8*)&T1eT_g[(nt*16 + l15)*32 + quad*8];
    float pb[4];
    #pragma unroll
    for (int r = 0; r < 4; r++)
        pb[r] = pwb[layer*64 + wave*16 + quad*4 + r];

    // x tile fill (both rows): layer 0 recomputes fc0; others load from xh
    if (layer == 0) {
        if (tid < 64) {
            wl[0][tid] = fc0w[tid]; wl[1][tid] = fc0w[64+tid];
            wl[2][tid] = fc0w[128+tid]; wl[3][tid] = fc0b[tid];
        }
        __syncthreads();
        int y = tid & 127, half = tid >> 7;
        #pragma unroll
        for (int r2 = 0; r2 < 2; r2++) {
            int p = (row0 + r2)*128 + y;
            float c = cnt[(size_t)b*Pg + p];
            float g = (c > 0.f) ? val[(size_t)b*Pg + p] / fmaxf(c, 1e-6f) : 0.f;
            float a1 = xg[p], a2 = yg[p];
            #pragma unroll
            for (int blk = 0; blk < 4; blk++) {
                f16x8 pkk;
                #pragma unroll
                for (int j = 0; j < 8; j++) {
                    int o = half*32 + blk*8 + j;
                    pkk[j] = (_Float16)(g*wl[0][o] + a1*wl[1][o] + a2*wl[2][o] + wl[3][o]);
                }
                *(f16x8*)&BsT[r2][y][half*32 + blk*8] = pkk;
            }
        }
    } else {
        for (int i = tid; i < 2048; i += 256) {
            int r2 = i >> 10, k = i & 1023;
            int y = k >> 3, seg = k & 7;
            *(float4*)&BsT[r2][y][seg*8] =
                ((const float4*)(xh + (size_t)(b*128 + row0 + r2) * 8192))[k];
        }
    }
    __syncthreads();

    // per-row MFMA + gelu into registers (acc reused across rows)
    f16x4 pk[2][8];
    #pragma unroll
    for (int r2 = 0; r2 < 2; r2++) {
        f32x4 acc[8];
        #pragma unroll
        for (int nt = 0; nt < 8; nt++) {
            f32x4 a = {0.f,0.f,0.f,0.f};
            f16x8 b0 = *(const f16x8*)&BsT[r2][nt*16 + l15][quad*8];
            f16x8 b1 = *(const f16x8*)&BsT[r2][nt*16 + l15][32 + quad*8];
            a = __builtin_amdgcn_mfma_f32_16x16x32_f16(af0, b0, a, 0, 0, 0);
            a = __builtin_amdgcn_mfma_f32_16x16x32_f16(af1, b1, a, 0, 0, 0);
            a = __builtin_amdgcn_mfma_f32_16x16x32_f16(af2[r2], b2a[nt], a, 0, 0, 0);
            acc[nt] = a;
        }
        #pragma unroll
        for (int nt = 0; nt < 8; nt++)
            #pragma unroll
            for (int r = 0; r < 4; r++)
                pk[r2][nt][r] = (_Float16)fast_gelu(acc[nt][r] + pb[r]);
    }
    __syncthreads();   // all BsT reads complete before overwrite

    // write gelu outputs into BsT
    #pragma unroll
    for (int r2 = 0; r2 < 2; r2++)
        #pragma unroll
        for (int nt = 0; nt < 8; nt++)
            *(f16x4*)&BsT[r2][nt*16 + l15][wave*16 + quad*4] = pk[r2][nt];
    __syncthreads();

    // x store (layer 2: only the two rows k_final will read)
    bool st0 = true, st1 = true;
    if (layer == 2) {
        float Lxf = fmaxf((float)Lx[0], 1e-6f);
        float x01 = fminf(fmaxf(xyt[b*3 + 0] / Lxf, 0.f), 1.f);
        float gxp = x01 * (NXg - 1);
        int x0 = (int)floorf(gxp);
        int x1 = min(x0 + 1, NXg - 1);
        st0 = (row0 == x0) || (row0 == x1);
        st1 = (row0 + 1 == x0) || (row0 + 1 == x1);
    }
    for (int i = tid; i < 2048; i += 256) {
        int r2 = i >> 10, k = i & 1023;
        if (r2 ? st1 : st0) {
            int y = k >> 3, seg = k & 7;
            ((float4*)(xh + (size_t)(b*128 + row0 + r2) * 8192))[k] =
                *(const float4*)&BsT[r2][y][seg*8];
        }
    }

    // stage-A for both rows; T1e fragments loaded once; direct Yg scatter
    f16x8 bf[8];
    stageA_bf(T1e_g, lane, bf);
    stageA_core(BsT[0], bf, Yg, b, row0, tid);
    stageA_core(BsT[1], bf, Yg, b, row0 + 1, tid);
}

// ---------------- final: layer-3 at 4 points + fc1 + fc2 + bilinear ----------------
__global__ __launch_bounds__(256) void k_final(const _Float16* __restrict__ x,
                    const _Float16* __restrict__ ofhr, const _Float16* __restrict__ ofhi,
                    const float* __restrict__ pw, const float* __restrict__ pwb,
                    const float* __restrict__ fc1w, const float* __restrict__ fc1b,
                    const float* __restrict__ fc2w, const float* __restrict__ fc2b,
                    const float* __restrict__ xyt, const int* __restrict__ Lx, const int* __restrict__ Ly,
                    const float* __restrict__ Tc, const float* __restrict__ Ts,
                    float* __restrict__ out) {
    __shared__ float y4[4][64];
    __shared__ float hh[4][129];
    __shared__ int   pxy[4][2];
    __shared__ float wxy[2];
    __shared__ float tc[128], ts[128];
    int b = blockIdx.x;
    if (threadIdx.x < 128) {
        tc[threadIdx.x] = Tc[threadIdx.x];
        ts[threadIdx.x] = Ts[threadIdx.x];
    }
    if (threadIdx.x == 0) {
        float Lxf = fmaxf((float)Lx[0], 1e-6f);
        float Lyf = fmaxf((float)Ly[0], 1e-6f);
        float x01 = fminf(fmaxf(xyt[b*3 + 0] / Lxf, 0.f), 1.f);
        float y01 = fminf(fmaxf(xyt[b*3 + 1] / Lyf, 0.f), 1.f);
        float gx = x01 * (NXg - 1), gy = y01 * (NYg - 1);
        int x0 = (int)floorf(gx), y0 = (int)floorf(gy);
        int x1 = min(x0 + 1, NXg - 1), y1 = min(y0 + 1, NYg - 1);
        wxy[0] = gx - (float)x0;
        wxy[1] = gy - (float)y0;
        pxy[0][0] = x0; pxy[0][1] = y0;
        pxy[1][0] = x1; pxy[1][1] = y0;
        pxy[2][0] = x0; pxy[2][1] = y1;
        pxy[3][0] = x1; pxy[3][1] = y1;
    }
    __syncthreads();
    {
        int p = threadIdx.x >> 6, o = threadIdx.x & 63;
        int px = pxy[p][0], py = pxy[p][1];
        float gkr[12], gki[12];
        #pragma unroll
        for (int ky = 0; ky < 12; ky++) { gkr[ky] = 0.f; gki[ky] = 0.f; }
        for (int kxi = 0; kxi < 24; kxi++) {
            int kx = (kxi < 12) ? kxi : (104 + kxi);
            int m = (kx * px) & 127;
            float cc = tc[m], ss = ts[m];
            #pragma unroll
            for (int ky = 0; ky < 12; ky++) {
                size_t idx = (size_t)(kxi*12 + ky)*4096 + b*64 + o;
                float a = (float)ofhr[idx], bb = (float)ofhi[idx];
                gkr[ky] += a*cc - bb*ss;
                gki[ky] += a*ss + bb*cc;
            }
        }
        float sp = gkr[0];
        #pragma unroll
        for (int ky = 1; ky < 12; ky++) {
            int m = (ky * py) & 127;
            sp += 2.f * (gkr[ky]*tc[m] - gki[ky]*ts[m]);
        }
        float s = 0.f;
        const _Float16* xb = x + ((size_t)(b*128 + px)*128 + py)*64;
        #pragma unroll 4
        for (int c = 0; c < 64; c++)
            s += pw[3*4096 + o*64 + c] * (float)xb[c];
        y4[p][o] = sp * (1.f/16384.f) + s + pwb[3*64 + o];
    }
    __syncthreads();
    for (int i = threadIdx.x; i < 512; i += 256) {
        int p = i >> 7, f = i & 127;
        float s = fc1b[f];
        #pragma unroll 4
        for (int w = 0; w < 64; w++) s += y4[p][w] * fc1w[w*128 + f];
        hh[p][f] = 0.5f * s * (1.f + erff(s * 0.70710678118654752f));
    }
    __syncthreads();
    if (threadIdx.x < 3) {
        int o3 = threadIdx.x;
        float f4[4];
        #pragma unroll
        for (int p = 0; p < 4; p++) {
            float s = fc2b[o3];
            #pragma unroll 4
            for (int f = 0; f < 128; f++) s += hh[p][f] * fc2w[f*3 + o3];
            f4[p] = s;
        }
        float wx = wxy[0], wy = wxy[1];
        float top = f4[0]*(1.f - wx) + f4[1]*wx;
        float bot = f4[2]*(1.f - wx) + f4[3]*wx;
        out[b*3 + o3] = top*(1.f - wy) + bot*wy;
    }
}

extern "C" void kernel_launch(void* const* d_in, const int* in_sizes, int n_in,
                              void* d_out, int out_size, void* d_ws, size_t ws_size,
                              hipStream_t stream) {
    const float* xyt    = (const float*)d_in[0];
    const float* obs_c  = (const float*)d_in[1];
    const float* obs_v  = (const float*)d_in[2];
    const float* xg     = (const float*)d_in[3];
    const float* yg     = (const float*)d_in[4];
    const float* fc0w   = (const float*)d_in[5];
    const float* fc0b   = (const float*)d_in[6];
    const float* w1r    = (const float*)d_in[7];
    const float* w1i    = (const float*)d_in[8];
    const float* w2r    = (const float*)d_in[9];
    const float* w2i    = (const float*)d_in[10];
    const float* pww    = (const float*)d_in[11];
    const float* pwb    = (const float*)d_in[12];
    const float* fc1w   = (const float*)d_in[13];
    const float* fc1b   = (const float*)d_in[14];
    const float* fc2w   = (const float*)d_in[15];
    const float* fc2b   = (const float*)d_in[16];
    const int*   nb     = (const int*)d_in[17];
    const int*   siy    = (const int*)d_in[18];
    const int*   six    = (const int*)d_in[19];
    const int*   Lx     = (const int*)d_in[20];
    const int*   Ly     = (const int*)d_in[21];
    float* out = (float*)d_out;

    float* W = (float*)d_ws;
    float* Tc  = W + OFF_TC;
    float* Ts  = W + OFF_TS;
    _Float16* Hbase = (_Float16*)(W + F32_END);
    _Float16* T1e_g  = Hbase + H_T1E;
    _Float16* T1eT_g = Hbase + H_T1ET;
    _Float16* A2_g   = Hbase + H_A2;
    _Float16* PWh    = Hbase + H_PWH;
    _Float16* T2eT_g = Hbase + H_T2ET;
    _Float16* xfhr   = Hbase + H_XFHR;
    _Float16* xfhi   = Hbase + H_XFHI;
    _Float16* ofhr   = Hbase + H_OFHR;
    _Float16* ofhi   = Hbase + H_OFHI;
    _Float16* Whr    = Hbase + H_WHR;
    _Float16* Whi    = Hbase + H_WHI;
    _Float16* Yg     = Hbase + H_YG;
    _Float16* xh     = Hbase + H_X;
    float*    val    = (float*)(Hbase + H_U);
    float*    cnt    = val + Bq*Pg;
    _Float16* Gh2    = Hbase + H_U + (size_t)4*Bq*Pg;   // after val/cnt (no alias)

    hipMemsetAsync(val, 0, (size_t)2 * Bq * Pg * sizeof(float), stream);

    k_prep<<<1104, 256, 0, stream>>>(T1e_g, T1eT_g, A2_g, pww, PWh, T2eT_g, Tc, Ts,
                                     xyt, obs_c, obs_v, nb, siy, six, val, cnt,
                                     w1r, w1i, w2r, w2i, Whr, Whi);
    k_fc0y<<<dim3(128, Bq), 256, 0, stream>>>(val, cnt, xg, yg, fc0w, fc0b, T1e_g, Yg);

    for (int l = 0; l < 3; l++) {
        k_sB<<<Bq*Wd/4, 256, 0, stream>>>(Yg, A2_g, xfhr, xfhi);
        k_s3m<<<dim3(288, 4), 256, 0, stream>>>(xfhr, xfhi, Whr, Whi, ofhr, ofhi, l);
        k_sG<<<dim3(Bq, 24), 256, 0, stream>>>(ofhr, ofhi, T2eT_g, Gh2);
        k_s45<<<dim3(64, Bq), 256, 0, stream>>>(xh, Gh2, T1e_g, T1eT_g, PWh, pwb, Yg, l,
                                                xyt, Lx, val, cnt, xg, yg, fc0w, fc0b);
    }
    // layer 3: spectral coefficients (MFMA path) + k_final
    k_sB<<<Bq*Wd/4, 256, 0, stream>>>(Yg, A2_g, xfhr, xfhi);
    k_s3m<<<dim3(288, 4), 256, 0, stream>>>(xfhr, xfhi, Whr, Whi, ofhr, ofhi, 3);
    k_final<<<Bq, 256, 0, stream>>>(xh, ofhr, ofhi, pww, pwb, fc1w, fc1b, fc2w, fc2b,
                                    xyt, Lx, Ly, Tc, Ts, out);
}